// Round 5
// baseline (318.574 us; speedup 1.0000x reference)
//
#include <hip/hip_runtime.h>

// SpatialTransformer: dense 2D bilinear warp with edge clamping.
// img: [B,C,H,W] fp32, trf: [B,2,H,W] fp32 (ij displacements), out: [B,C,H,W] fp32.
// B=16, C=4, H=W=768.
//
// R6: attack the ~30cyc/vmem-wave-instruction rate limit (R4/R5: time invariant
// under 2x occupancy; VALU 21%, HBM 28%). R5 issued 16 scalar vmem instrs per
// output px. R6 makes EVERY global access dwordx4: planar padded LDS tile
// (row stride 84 floats = 336B, 16B-aligned) so staging is float4 load ->
// ds_write_b128 (conflict-free), trf loads and out stores are float4 (each
// thread owns 4 consecutive px of one row). Vmem instrs: 16/px -> 4/px.
// Gathers: 16 ds_read_b32/px with compile-time channel-slice offsets.

typedef float fvec4 __attribute__((ext_vector_type(4)));

#define BB 16
#define CC 4
#define HH 768
#define WW 768
#define HWSZ (HH * WW)

#define TW 64
#define TH 32
#define HALO 8
#define TLW (TW + 2 * HALO)          // 80
#define TLH (TH + 2 * HALO)          // 48
#define LSTR 84                      // padded LDS row stride (floats); 336B, 16B-aligned
#define SLICE (TLH * LSTR)           // 4032 floats per channel plane
#define NCHK (TLH * (TLW / 4))       // 960 float4-chunks per channel
#define TCHK (CC * NCHK)             // 3840 staging chunks
#define NXT (WW / TW)                // 12
#define NYT (HH / TH)                // 24
#define TILES_PER_B (NXT * NYT)      // 288
#define NTILES (TILES_PER_B * BB)    // 4608
#define NXCD 8
#define NTHR 512                     // 8 waves; thread owns 4 px of one row

__global__ __launch_bounds__(NTHR) void st_warp_lds4(
    const float* __restrict__ img,
    const float* __restrict__ trf,
    float* __restrict__ out)
{
    __shared__ float lds[CC * SLICE];   // 64512 B -> 2 blocks/CU

    // XCD-aware swizzle: block l -> XCD l%8; each XCD walks ht fastest down a
    // 64-wide column band so vertically-adjacent tiles' halos overlap in L2.
    int l = blockIdx.x;
    int xcd = l & (NXCD - 1);
    int t = xcd * (NTILES / NXCD) + (l >> 3);
    int b = t / TILES_PER_B;
    int rem = t - b * TILES_PER_B;
    int wt = rem / NYT;
    int ht = rem - wt * NYT;
    int h0 = ht * TH, w0 = wt * TW;
    int oy = h0 - HALO, ox = w0 - HALO;

    const float* ib = img + (size_t)b * CC * HWSZ;
    const float* tb = trf + (size_t)b * 2 * HWSZ;
    float* ob = out + (size_t)b * CC * HWSZ;

    int tid = threadIdx.x;
    int rrow = tid >> 4;               // 0..31: row in tile
    int xg = tid & 15;                 // 0..15: which float4 group in the row
    int h = h0 + rrow;
    int x0 = w0 + xg * 4;

    // trf loads first (float4, nontemporal): latency hides under staging.
    int ptr0 = h * WW + x0;
    fvec4 dy4 = __builtin_nontemporal_load(reinterpret_cast<const fvec4*>(tb + ptr0));
    fvec4 dx4 = __builtin_nontemporal_load(reinterpret_cast<const fvec4*>(tb + HWSZ + ptr0));

    // Stage img tile+halo into planar padded LDS. One float4 plane load ->
    // one ds_write_b128 per chunk; rows 336B so every write is 16B-aligned
    // and lane-consecutive (conflict-free).
#pragma unroll
    for (int i = 0; i < (TCHK + NTHR - 1) / NTHR; ++i) {
        int s = tid + i * NTHR;
        if (s < TCHK) {
            int c = s / NCHK;                       // magic-mul
            int r = s - c * NCHK;
            int ly = r / (TLW / 4);                 // /20, magic-mul
            int g = r - ly * (TLW / 4);
            int lx0 = g * 4;
            int gy = min(max(oy + ly, 0), HH - 1);
            int gxr = ox + lx0;
            int gx0 = min(max(gxr, 0), WW - 4);
            fvec4 v = *reinterpret_cast<const fvec4*>(ib + (size_t)c * HWSZ + gy * WW + gx0);
            if (gxr != gx0) {                       // edge columns only: remap components
                fvec4 u;
#pragma unroll
                for (int j = 0; j < 4; ++j) {
                    int d = min(max(gxr + j, 0), WW - 1) - gx0;
                    u[j] = v[d];
                }
                v = u;
            }
            *reinterpret_cast<fvec4*>(&lds[c * SLICE + ly * LSTR + lx0]) = v;
        }
    }
    __syncthreads();

    const float maxy = (float)(HH - 1);
    const float maxx = (float)(WW - 1);

    float o0[4], o1[4], o2[4], o3[4];   // per-channel results for the 4 px

#pragma unroll
    for (int j = 0; j < 4; ++j) {
        float y = (float)h + dy4[j];
        float x = (float)(x0 + j) + dx4[j];

        float cy = fminf(fmaxf(y, 0.0f), maxy);
        float cx = fminf(fmaxf(x, 0.0f), maxx);

        float f0y = fminf(fmaxf(floorf(y), 0.0f), maxy);
        float f0x = fminf(fmaxf(floorf(x), 0.0f), maxx);
        float f1y = fminf(f0y + 1.0f, maxy);
        float f1x = fminf(f0x + 1.0f, maxx);

        // neurite convention: weight of floor corner = loc1 - clipped
        float wy0 = f1y - cy;
        float wx0 = f1x - cx;
        float wy1 = 1.0f - wy0;
        float wx1 = 1.0f - wx0;

        int i0y = (int)f0y;
        int i0x = (int)f0x;
        int i1y = (int)f1y;
        int i1x = (int)f1x;

        float w00 = wy0 * wx0;
        float w01 = wy0 * wx1;
        float w10 = wy1 * wx0;
        float w11 = wy1 * wx1;

        if (i0y >= oy && i1y <= oy + TLH - 1 && i0x >= ox && i1x <= ox + TLW - 1) {
            // In staged tile (always true for |disp| <= HALO).
            int a00 = (i0y - oy) * LSTR + (i0x - ox);
            int ddx = i1x - i0x;                    // 0 or 1
            int ddy = (i1y - i0y) * LSTR;
            int a01 = a00 + ddx;
            int a10 = a00 + ddy;
            int a11 = a10 + ddx;
            // c*SLICE is compile-time -> folds to ds_read offset: immediates.
            o0[j] = w00 * lds[a00] + w01 * lds[a01] + w10 * lds[a10] + w11 * lds[a11];
            o1[j] = w00 * lds[SLICE + a00] + w01 * lds[SLICE + a01]
                  + w10 * lds[SLICE + a10] + w11 * lds[SLICE + a11];
            o2[j] = w00 * lds[2 * SLICE + a00] + w01 * lds[2 * SLICE + a01]
                  + w10 * lds[2 * SLICE + a10] + w11 * lds[2 * SLICE + a11];
            o3[j] = w00 * lds[3 * SLICE + a00] + w01 * lds[3 * SLICE + a01]
                  + w10 * lds[3 * SLICE + a10] + w11 * lds[3 * SLICE + a11];
        } else {
            // Rare (never on N(0,1) inputs): global planar gather fallback.
            int g00 = i0y * WW + i0x;
            int g01 = i0y * WW + i1x;
            int g10 = i1y * WW + i0x;
            int g11 = i1y * WW + i1x;
            o0[j] = w00 * ib[g00] + w01 * ib[g01] + w10 * ib[g10] + w11 * ib[g11];
            o1[j] = w00 * ib[HWSZ + g00] + w01 * ib[HWSZ + g01]
                  + w10 * ib[HWSZ + g10] + w11 * ib[HWSZ + g11];
            o2[j] = w00 * ib[2 * HWSZ + g00] + w01 * ib[2 * HWSZ + g01]
                  + w10 * ib[2 * HWSZ + g10] + w11 * ib[2 * HWSZ + g11];
            o3[j] = w00 * ib[3 * HWSZ + g00] + w01 * ib[3 * HWSZ + g01]
                  + w10 * ib[3 * HWSZ + g10] + w11 * ib[3 * HWSZ + g11];
        }
    }

    // One float4 nontemporal store per channel: 4 vmem instrs for 16 outputs.
    fvec4 s0 = { o0[0], o0[1], o0[2], o0[3] };
    fvec4 s1 = { o1[0], o1[1], o1[2], o1[3] };
    fvec4 s2 = { o2[0], o2[1], o2[2], o2[3] };
    fvec4 s3 = { o3[0], o3[1], o3[2], o3[3] };
    __builtin_nontemporal_store(s0, reinterpret_cast<fvec4*>(ob + ptr0));
    __builtin_nontemporal_store(s1, reinterpret_cast<fvec4*>(ob + HWSZ + ptr0));
    __builtin_nontemporal_store(s2, reinterpret_cast<fvec4*>(ob + 2 * HWSZ + ptr0));
    __builtin_nontemporal_store(s3, reinterpret_cast<fvec4*>(ob + 3 * HWSZ + ptr0));
}

extern "C" void kernel_launch(void* const* d_in, const int* in_sizes, int n_in,
                              void* d_out, int out_size, void* d_ws, size_t ws_size,
                              hipStream_t stream) {
    const float* img = (const float*)d_in[0];
    const float* trf = (const float*)d_in[1];
    float* out = (float*)d_out;

    st_warp_lds4<<<NTILES, NTHR, 0, stream>>>(img, trf, out);
}

// Round 7
// 312.085 us; speedup vs baseline: 1.0208x; 1.0208x over previous
//
#include <hip/hip_runtime.h>

// SpatialTransformer: dense 2D bilinear warp with edge clamping.
// img: [B,C,H,W] fp32, trf: [B,2,H,W] fp32 (ij displacements), out: [B,C,H,W] fp32.
// B=16, C=4, H=W=768.
//
// R8 (= R7 resubmit after container infra failure): minimal-on-every-pipe
// variant. Interleaved float4 LDS tile (4 ds_read_b128 per px gather,
// R4/R5's measured-low-conflict path) PLUS all global IO as dwordx4 (R6's
// vmem cut) — made compatible by a plane-split LDS swizzle: px s -> slot
// 961*(s&3) + (s>>2). Staging ds_write_b128 then has exact 16B lane stride
// (conflict-free); gather reads spread across bank quads. Per thread:
// 14 x4 vmem + 24 b128 DS + ~180 VALU cycles. Discriminates H1 (composite
// pipe sum -> expect 85-100us) vs H2 (external ~2.3TB/s effective memory
// ceiling -> expect ~115us invariant).

typedef float fvec4 __attribute__((ext_vector_type(4)));

#define BB 16
#define CC 4
#define HH 768
#define WW 768
#define HWSZ (HH * WW)

#define TW 64
#define TH 32
#define HALO 8
#define TLW (TW + 2 * HALO)          // 80
#define TLH (TH + 2 * HALO)          // 48
#define TILE_PX (TLH * TLW)          // 3840 staged pixels
#define NCHK (TILE_PX / 4)           // 960 4-px chunks
#define CPR (TLW / 4)                // 20 chunks per tile row
#define PLANE 961                    // slot-plane stride (odd in 16B units: banks spread)
#define NSLOT (4 * PLANE)            // 3844 fvec4 slots = 61504 B
#define NXT (WW / TW)                // 12
#define NYT (HH / TH)                // 24
#define TILES_PER_B (NXT * NYT)      // 288
#define NTILES (TILES_PER_B * BB)    // 4608
#define NXCD 8
#define NTHR 512                     // 8 waves; thread owns 4 px of one row

// px index s (row-major in TLH x TLW tile) -> interleaved-tile slot
__device__ __forceinline__ int slot_of(int s) {
    return PLANE * (s & 3) + (s >> 2);
}

__global__ __launch_bounds__(NTHR) void st_warp_v4(
    const float* __restrict__ img,
    const float* __restrict__ trf,
    float* __restrict__ out)
{
    __shared__ fvec4 tile[NSLOT];    // 61504 B -> 2 blocks/CU

    // XCD-aware swizzle: block l -> XCD l%8; each XCD walks ht fastest down a
    // 64-wide column band so vertically-adjacent tiles' halos overlap in L2.
    int l = blockIdx.x;
    int xcd = l & (NXCD - 1);
    int t = xcd * (NTILES / NXCD) + (l >> 3);
    int b = t / TILES_PER_B;
    int rem = t - b * TILES_PER_B;
    int wt = rem / NYT;
    int ht = rem - wt * NYT;
    int h0 = ht * TH, w0 = wt * TW;
    int oy = h0 - HALO, ox = w0 - HALO;

    const float* ib = img + (size_t)b * CC * HWSZ;
    const float* tb = trf + (size_t)b * 2 * HWSZ;
    float* ob = out + (size_t)b * CC * HWSZ;

    int tid = threadIdx.x;
    int rrow = tid >> 4;               // 0..31: output row in tile
    int xg = tid & 15;                 // 0..15: float4 group in the row
    int h = h0 + rrow;
    int x0 = w0 + xg * 4;
    int ptr0 = h * WW + x0;

    // trf loads first (x4, nontemporal): latency hides under staging.
    fvec4 dy4 = __builtin_nontemporal_load(reinterpret_cast<const fvec4*>(tb + ptr0));
    fvec4 dx4 = __builtin_nontemporal_load(reinterpret_cast<const fvec4*>(tb + HWSZ + ptr0));

    // ---- Stage img tile+halo: 4-px chunks, x4 plane loads -> repack ->
    // 4 ds_write_b128 at 16B lane stride (conflict-free). 960 chunks over
    // 512 threads: pass 0 = all, pass 1 = waves 0..6 (wave-uniform guard).
#pragma unroll
    for (int pass = 0; pass < 2; ++pass) {
        int q = tid + pass * NTHR;
        if (pass == 1 && tid >= NCHK - NTHR) break;   // tid>=448: wave 7 exits
        int ly = q / CPR;                  // /20 -> magic mul
        int lx0 = (q - ly * CPR) * 4;
        int gy = min(max(oy + ly, 0), HH - 1);
        int gxr = ox + lx0;
        int gx0 = min(max(gxr, 0), WW - 4);
        const float* base = ib + gy * WW + gx0;
        fvec4 p0 = *reinterpret_cast<const fvec4*>(base);
        fvec4 p1 = *reinterpret_cast<const fvec4*>(base + HWSZ);
        fvec4 p2 = *reinterpret_cast<const fvec4*>(base + 2 * HWSZ);
        fvec4 p3 = *reinterpret_cast<const fvec4*>(base + 3 * HWSZ);
        if (gxr != gx0) {                  // edge chunk: remap components
            int d0 = min(max(gxr + 0, 0), WW - 1) - gx0;
            int d1 = min(max(gxr + 1, 0), WW - 1) - gx0;
            int d2 = min(max(gxr + 2, 0), WW - 1) - gx0;
            int d3 = min(max(gxr + 3, 0), WW - 1) - gx0;
            p0 = fvec4{p0[d0], p0[d1], p0[d2], p0[d3]};
            p1 = fvec4{p1[d0], p1[d1], p1[d2], p1[d3]};
            p2 = fvec4{p2[d0], p2[d1], p2[d2], p2[d3]};
            p3 = fvec4{p3[d0], p3[d1], p3[d2], p3[d3]};
        }
        // px 4q+k -> slot PLANE*k + q
        tile[0 * PLANE + q] = fvec4{p0[0], p1[0], p2[0], p3[0]};
        tile[1 * PLANE + q] = fvec4{p0[1], p1[1], p2[1], p3[1]};
        tile[2 * PLANE + q] = fvec4{p0[2], p1[2], p2[2], p3[2]};
        tile[3 * PLANE + q] = fvec4{p0[3], p1[3], p2[3], p3[3]};
    }
    __syncthreads();

    const float maxy = (float)(HH - 1);
    const float maxx = (float)(WW - 1);

    fvec4 res[4];                        // per-px channel vectors

#pragma unroll
    for (int j = 0; j < 4; ++j) {
        float y = (float)h + dy4[j];
        float x = (float)(x0 + j) + dx4[j];

        float cy = fminf(fmaxf(y, 0.0f), maxy);
        float cx = fminf(fmaxf(x, 0.0f), maxx);

        float f0y = fminf(fmaxf(floorf(y), 0.0f), maxy);
        float f0x = fminf(fmaxf(floorf(x), 0.0f), maxx);
        float f1y = fminf(f0y + 1.0f, maxy);
        float f1x = fminf(f0x + 1.0f, maxx);

        // neurite convention: weight of floor corner = loc1 - clipped
        float wy0 = f1y - cy;
        float wx0 = f1x - cx;
        float wy1 = 1.0f - wy0;
        float wx1 = 1.0f - wx0;

        int i0y = (int)f0y;
        int i0x = (int)f0x;
        int i1y = (int)f1y;
        int i1x = (int)f1x;

        float w00 = wy0 * wx0;
        float w01 = wy0 * wx1;
        float w10 = wy1 * wx0;
        float w11 = wy1 * wx1;

        if (i0y >= oy && i1y <= oy + TLH - 1 && i0x >= ox && i1x <= ox + TLW - 1) {
            int s00 = (i0y - oy) * TLW + (i0x - ox);
            int ddx = i1x - i0x;               // 0 or 1
            int s10 = s00 + (i1y - i0y) * TLW;
            fvec4 c00 = tile[slot_of(s00)];
            fvec4 c01 = tile[slot_of(s00 + ddx)];
            fvec4 c10 = tile[slot_of(s10)];
            fvec4 c11 = tile[slot_of(s10 + ddx)];
            res[j] = w00 * c00 + w01 * c01 + w10 * c10 + w11 * c11;
        } else {
            // Rare (never on N(0,1) inputs): global planar gather fallback.
            int g00 = i0y * WW + i0x;
            int g01 = i0y * WW + i1x;
            int g10 = i1y * WW + i0x;
            int g11 = i1y * WW + i1x;
            fvec4 v;
#pragma unroll
            for (int c = 0; c < CC; ++c) {
                const float* ic = ib + c * HWSZ;
                v[c] = w00 * ic[g00] + w01 * ic[g01]
                     + w10 * ic[g10] + w11 * ic[g11];
            }
            res[j] = v;
        }
    }

    // One x4 nontemporal store per channel (4 vmem instrs for 16 outputs).
    fvec4 s0 = {res[0][0], res[1][0], res[2][0], res[3][0]};
    fvec4 s1 = {res[0][1], res[1][1], res[2][1], res[3][1]};
    fvec4 s2 = {res[0][2], res[1][2], res[2][2], res[3][2]};
    fvec4 s3 = {res[0][3], res[1][3], res[2][3], res[3][3]};
    __builtin_nontemporal_store(s0, reinterpret_cast<fvec4*>(ob + ptr0));
    __builtin_nontemporal_store(s1, reinterpret_cast<fvec4*>(ob + HWSZ + ptr0));
    __builtin_nontemporal_store(s2, reinterpret_cast<fvec4*>(ob + 2 * HWSZ + ptr0));
    __builtin_nontemporal_store(s3, reinterpret_cast<fvec4*>(ob + 3 * HWSZ + ptr0));
}

extern "C" void kernel_launch(void* const* d_in, const int* in_sizes, int n_in,
                              void* d_out, int out_size, void* d_ws, size_t ws_size,
                              hipStream_t stream) {
    const float* img = (const float*)d_in[0];
    const float* trf = (const float*)d_in[1];
    float* out = (float*)d_out;

    st_warp_v4<<<NTILES, NTHR, 0, stream>>>(img, trf, out);
}